// Round 1
// baseline (444.318 us; speedup 1.0000x reference)
//
#include <hip/hip_runtime.h>
#include <math.h>

// Problem constants
#define QN 4096
#define MN 65536
#define DN 384
#define CN 128
#define NCHUNK 32                 // m-chunks (grid.y of GEMM)
#define MROWS_PER_CHUNK (MN / NCHUNK)   // 2048
#define MT_PER (MROWS_PER_CHUNK / 128)  // 16 m-tiles per block

typedef __attribute__((ext_vector_type(8))) short bf16x8;  // 8 bf16 = 4 VGPRs
typedef __attribute__((ext_vector_type(4))) float f32x4;

__device__ __forceinline__ unsigned short f2bf(float f) {
  unsigned int u = __float_as_uint(f);
  unsigned int r = (u + 0x7fffu + ((u >> 16) & 1u)) >> 16;  // RNE
  return (unsigned short)r;
}

__device__ __forceinline__ void async16(const void* g, void* l) {
  __builtin_amdgcn_global_load_lds(
      (const __attribute__((address_space(1))) unsigned int*)g,
      (__attribute__((address_space(3))) unsigned int*)l, 16, 0, 0);
}

// ---------------- Kernel A: L2-normalize rows, cast to bf16 ----------------
__global__ void nrm_kernel(const float* __restrict__ x,
                           unsigned short* __restrict__ y) {
  const int r = blockIdx.x;
  const int t = threadIdx.x;  // 128 threads
  const float* xr = x + (size_t)r * DN;
  float v0 = xr[t], v1 = xr[t + 128], v2 = xr[t + 256];
  float ss = v0 * v0 + v1 * v1 + v2 * v2;
#pragma unroll
  for (int m = 1; m < 64; m <<= 1) ss += __shfl_xor(ss, m);
  __shared__ float w[2];
  if ((t & 63) == 0) w[t >> 6] = ss;
  __syncthreads();
  const float tot = w[0] + w[1];
  const float scale = 1.0f / fmaxf(sqrtf(tot), 1e-8f);
  unsigned short* yr = y + (size_t)r * DN;
  yr[t] = f2bf(v0 * scale);
  yr[t + 128] = f2bf(v1 * scale);
  yr[t + 256] = f2bf(v2 * scale);
}

// ------------- Kernel B: bf16 MFMA GEMM with fused row-max (m97 shape) -----
__global__ __launch_bounds__(256, 2) void gemm_max_kernel(
    const unsigned short* __restrict__ qn, const unsigned short* __restrict__ mn,
    float* __restrict__ pmax) {
  __shared__ unsigned short As[128 * 64];  // 16 KB  [qrow][k]
  __shared__ unsigned short Bs[128 * 64];  // 16 KB  [mrow][k]
  __shared__ float smax[2][128];

  const int tid = threadIdx.x;
  const int wave = tid >> 6, lane = tid & 63;
  const int wr = wave >> 1, wc = wave & 1;       // 2x2 wave grid, 64x64 each
  const int quad = lane >> 4, l16 = lane & 15;
  const int qrow0 = blockIdx.x * 128;
  const int mchunk0 = blockIdx.y * MROWS_PER_CHUNK;

  const int srow = lane >> 3;       // staging: 8 rows / issue
  const int scol = (lane & 7) * 8;  // 8 bf16 = 16 B per lane

  float rmax[16];
#pragma unroll
  for (int i = 0; i < 16; ++i) rmax[i] = -3.0e38f;

#pragma unroll 1
  for (int mt = 0; mt < MT_PER; ++mt) {
    const int mrow0 = mchunk0 + mt * 128;
    f32x4 acc[4][4];
#pragma unroll
    for (int rt = 0; rt < 4; ++rt)
#pragma unroll
      for (int ct = 0; ct < 4; ++ct) acc[rt][ct] = (f32x4){0.f, 0.f, 0.f, 0.f};

#pragma unroll 1
    for (int kc = 0; kc < DN / 64; ++kc) {
      const int k0 = kc * 64;
      // stage A (128x64) + B (128x64): each wave 4+4 x 1KB async issues
#pragma unroll
      for (int i = 0; i < 4; ++i) {
        const int rbase = wave * 32 + i * 8;
        const unsigned short* ga =
            qn + (size_t)(qrow0 + rbase + srow) * DN + (k0 + scol);
        async16(ga, &As[rbase * 64]);
        const unsigned short* gb =
            mn + (size_t)(mrow0 + rbase + srow) * DN + (k0 + scol);
        async16(gb, &Bs[rbase * 64]);
      }
      __syncthreads();  // drains vmcnt (async LDS writes visible)
#pragma unroll
      for (int ks = 0; ks < 2; ++ks) {
        bf16x8 af[4], bfr[4];
        const int kofs = ks * 32 + quad * 8;
#pragma unroll
        for (int rt = 0; rt < 4; ++rt)
          af[rt] = *(const bf16x8*)&As[(wr * 64 + rt * 16 + l16) * 64 + kofs];
#pragma unroll
        for (int ct = 0; ct < 4; ++ct)
          bfr[ct] = *(const bf16x8*)&Bs[(wc * 64 + ct * 16 + l16) * 64 + kofs];
#pragma unroll
        for (int rt = 0; rt < 4; ++rt)
#pragma unroll
          for (int ct = 0; ct < 4; ++ct)
            acc[rt][ct] = __builtin_amdgcn_mfma_f32_16x16x32_bf16(
                af[rt], bfr[ct], acc[rt][ct], 0, 0, 0);
      }
      __syncthreads();  // protect LDS before next stage
    }
    // epilogue: fold 4 col-tiles into running per-row max (1 vmax / element)
#pragma unroll
    for (int rt = 0; rt < 4; ++rt)
#pragma unroll
      for (int r = 0; r < 4; ++r) {
        float v = fmaxf(fmaxf(acc[rt][0][r], acc[rt][1][r]),
                        fmaxf(acc[rt][2][r], acc[rt][3][r]));
        rmax[rt * 4 + r] = fmaxf(rmax[rt * 4 + r], v);
      }
  }

  // butterfly max across the 16 lanes holding the same C row
#pragma unroll
  for (int i = 0; i < 16; ++i) {
    float v = rmax[i];
    v = fmaxf(v, __shfl_xor(v, 1));
    v = fmaxf(v, __shfl_xor(v, 2));
    v = fmaxf(v, __shfl_xor(v, 4));
    v = fmaxf(v, __shfl_xor(v, 8));
    rmax[i] = v;
  }
  if (l16 == 0) {
#pragma unroll
    for (int rt = 0; rt < 4; ++rt)
#pragma unroll
      for (int r = 0; r < 4; ++r)
        smax[wc][wr * 64 + rt * 16 + quad * 4 + r] = rmax[rt * 4 + r];
  }
  __syncthreads();
  if (tid < 128) {
    const float v = fmaxf(smax[0][tid], smax[1][tid]);
    pmax[(size_t)(qrow0 + tid) * NCHUNK + blockIdx.y] = v;
  }
}

// ------- Kernel C: reduce partial maxes; uniform rows; flag borderline ------
__global__ void reduce_kernel(const float* __restrict__ pmax,
                              float* __restrict__ out, int* __restrict__ flags) {
  const int idx = blockIdx.x * 256 + threadIdx.x;  // < QN*CN
  const int q = idx >> 7, c = idx & 127;
  const float* p = pmax + (size_t)q * NCHUNK;
  float mx = p[0];
#pragma unroll
  for (int j = 1; j < NCHUNK; ++j) mx = fmaxf(mx, p[j]);
  const bool flag = mx > 0.68f;  // 0.7 minus bf16-error margin (<=~0.01)
  if (c == 0) flags[q] = flag ? 1 : 0;
  if (!flag) out[idx] = 1.0f / 128.0f;
}

// ------- Kernel D: exact fp32 decision for flagged queries (rare path) ------
__global__ void exact_kernel(const float* __restrict__ qe,
                             const float* __restrict__ me,
                             const float* __restrict__ labels,
                             const int* __restrict__ flags,
                             float* __restrict__ out) {
  const int q = blockIdx.x;
  if (!flags[q]) return;
  const int t = threadIdx.x;  // 256
  __shared__ float sred[256];
  __shared__ int sidx[256];
  __shared__ float wsum[4];
  const float* qr = qe + (size_t)q * DN;
  float ss = 0.f;
  for (int i = t; i < DN; i += 256) ss += qr[i] * qr[i];
#pragma unroll
  for (int m = 1; m < 64; m <<= 1) ss += __shfl_xor(ss, m);
  if ((t & 63) == 0) wsum[t >> 6] = ss;
  __syncthreads();
  const float qnorm = fmaxf(sqrtf(wsum[0] + wsum[1] + wsum[2] + wsum[3]), 1e-8f);

  float best = -3.0e38f;
  int bidx = 0x7fffffff;
  for (int j = t; j < MN; j += 256) {
    const float* mr = me + (size_t)j * DN;
    float dot = 0.f, ms = 0.f;
    for (int k = 0; k < DN; ++k) {
      float a = qr[k], b = mr[k];
      dot += a * b;
      ms += b * b;
    }
    const float sim = dot / (qnorm * fmaxf(sqrtf(ms), 1e-8f));
    if (sim > best) { best = sim; bidx = j; }  // strict > keeps first index
  }
  sred[t] = best;
  sidx[t] = bidx;
  __syncthreads();
  for (int s = 128; s > 0; s >>= 1) {
    if (t < s) {
      const float ov = sred[t + s];
      const int oi = sidx[t + s];
      if (ov > sred[t] || (ov == sred[t] && oi < sidx[t])) {
        sred[t] = ov;
        sidx[t] = oi;
      }
    }
    __syncthreads();
  }
  const float mx = sred[0];
  const int mi = sidx[0];
  if (t < 128)
    out[(size_t)q * CN + t] =
        (mx > 0.7f) ? labels[(size_t)mi * CN + t] : (1.0f / 128.0f);
}

extern "C" void kernel_launch(void* const* d_in, const int* in_sizes, int n_in,
                              void* d_out, int out_size, void* d_ws,
                              size_t ws_size, hipStream_t stream) {
  const float* qe = (const float*)d_in[0];  // [4096,384] f32
  const float* me = (const float*)d_in[1];  // [65536,384] f32
  const float* lb = (const float*)d_in[2];  // [65536,128] f32
  float* out = (float*)d_out;               // [4096,128] f32

  char* ws = (char*)d_ws;
  const size_t OFF_QN = 0;
  const size_t OFF_MN = OFF_QN + (size_t)QN * DN * 2;             // 3,145,728
  const size_t OFF_PMAX = OFF_MN + (size_t)MN * DN * 2;           // +50,331,648
  const size_t OFF_FLAGS = OFF_PMAX + (size_t)QN * NCHUNK * 4;    // +524,288
  unsigned short* qn = (unsigned short*)(ws + OFF_QN);
  unsigned short* mn = (unsigned short*)(ws + OFF_MN);
  float* pmax = (float*)(ws + OFF_PMAX);
  int* flags = (int*)(ws + OFF_FLAGS);

  nrm_kernel<<<QN, 128, 0, stream>>>(qe, qn);
  nrm_kernel<<<MN, 128, 0, stream>>>(me, mn);
  gemm_max_kernel<<<dim3(QN / 128, NCHUNK), 256, 0, stream>>>(qn, mn, pmax);
  reduce_kernel<<<(QN * CN) / 256, 256, 0, stream>>>(pmax, out, flags);
  exact_kernel<<<QN, 256, 0, stream>>>(qe, me, lb, flags, out);
}

// Round 2
// 401.184 us; speedup vs baseline: 1.1075x; 1.1075x over previous
//
#include <hip/hip_runtime.h>
#include <math.h>

// Problem constants
#define QN 4096
#define MN 65536
#define DN 384
#define CN 128
#define NCHUNK 32                 // m-chunks (grid.y of GEMM)
#define MROWS_PER_CHUNK (MN / NCHUNK)   // 2048
#define MT_PER (MROWS_PER_CHUNK / 128)  // 16 m-tiles per block

typedef __attribute__((ext_vector_type(8))) short bf16x8;  // 8 bf16 = 4 VGPRs
typedef __attribute__((ext_vector_type(4))) float f32x4;

__device__ __forceinline__ unsigned short f2bf(float f) {
  unsigned int u = __float_as_uint(f);
  unsigned int r = (u + 0x7fffu + ((u >> 16) & 1u)) >> 16;  // RNE
  return (unsigned short)r;
}

__device__ __forceinline__ void async16(const void* g, void* l) {
  __builtin_amdgcn_global_load_lds(
      (const __attribute__((address_space(1))) unsigned int*)g,
      (__attribute__((address_space(3))) unsigned int*)l, 16, 0, 0);
}

// ------------- Kernel A: L2-normalize rows -> bf16, one wave per row -------
__global__ __launch_bounds__(256) void nrm_kernel(const float* __restrict__ x,
                                                  unsigned short* __restrict__ y,
                                                  int nrows) {
  const int row = blockIdx.x * 4 + (threadIdx.x >> 6);
  const int lane = threadIdx.x & 63;
  if (row >= nrows) return;
  const float* xr = x + (size_t)row * DN;
  float v[6];
  float ss = 0.f;
#pragma unroll
  for (int i = 0; i < 6; ++i) {
    v[i] = xr[lane + i * 64];
    ss += v[i] * v[i];
  }
#pragma unroll
  for (int m = 1; m < 64; m <<= 1) ss += __shfl_xor(ss, m);
  const float scale = 1.0f / fmaxf(sqrtf(ss), 1e-8f);
  unsigned short* yr = y + (size_t)row * DN;
#pragma unroll
  for (int i = 0; i < 6; ++i) yr[lane + i * 64] = f2bf(v[i] * scale);
}

// ------------- Kernel B: bf16 MFMA GEMM with fused row-max, XOR-swizzled ---
// LDS layout: tile row r (64 bf16 = 8 chunks of 16B). LDS chunk (r*8 + j)
// holds GLOBAL k-chunk (j ^ (r&7)) of row r. Staging picks the source per
// lane (free); reads use chunk kq^(r&7) -> quad's 16 lanes spread over all
// 32 banks (2-way = free) instead of 16-way same-bank.
__global__ __launch_bounds__(256, 2) void gemm_max_kernel(
    const unsigned short* __restrict__ qn, const unsigned short* __restrict__ mn,
    float* __restrict__ pmax) {
  __shared__ unsigned short As[128 * 64];  // 16 KB
  __shared__ unsigned short Bs[128 * 64];  // 16 KB
  __shared__ float smax[2][128];

  const int tid = threadIdx.x;
  const int wave = tid >> 6, lane = tid & 63;
  const int wr = wave >> 1, wc = wave & 1;       // 2x2 wave grid, 64x64 each
  const int quad = lane >> 4, l16 = lane & 15;
  const int l8 = l16 & 7;                        // row&7 for fragment reads
  const int qrow0 = blockIdx.x * 128;
  const int mchunk0 = blockIdx.y * MROWS_PER_CHUNK;

  const int srow = lane >> 3;                    // staging: 8 rows / issue
  const int scol = ((lane & 7) ^ srow) * 8;      // swizzled source k-chunk

  float rmax[16];
#pragma unroll
  for (int i = 0; i < 16; ++i) rmax[i] = -3.0e38f;

#pragma unroll 1
  for (int mt = 0; mt < MT_PER; ++mt) {
    const int mrow0 = mchunk0 + mt * 128;
    f32x4 acc[4][4];
#pragma unroll
    for (int rt = 0; rt < 4; ++rt)
#pragma unroll
      for (int ct = 0; ct < 4; ++ct) acc[rt][ct] = (f32x4){0.f, 0.f, 0.f, 0.f};

#pragma unroll 1
    for (int kc = 0; kc < DN / 64; ++kc) {
      const int k0 = kc * 64;
#pragma unroll
      for (int i = 0; i < 4; ++i) {
        const int rbase = wave * 32 + i * 8;
        const unsigned short* ga =
            qn + (size_t)(qrow0 + rbase + srow) * DN + (k0 + scol);
        async16(ga, &As[rbase * 64]);
        const unsigned short* gb =
            mn + (size_t)(mrow0 + rbase + srow) * DN + (k0 + scol);
        async16(gb, &Bs[rbase * 64]);
      }
      __syncthreads();
#pragma unroll
      for (int ks = 0; ks < 2; ++ks) {
        bf16x8 af[4], bfr[4];
        const int kq = ks * 4 + quad;            // k-chunk index 0..7
        const int kofs = (kq ^ l8) * 8;          // swizzled LDS chunk
#pragma unroll
        for (int rt = 0; rt < 4; ++rt)
          af[rt] = *(const bf16x8*)&As[(wr * 64 + rt * 16 + l16) * 64 + kofs];
#pragma unroll
        for (int ct = 0; ct < 4; ++ct)
          bfr[ct] = *(const bf16x8*)&Bs[(wc * 64 + ct * 16 + l16) * 64 + kofs];
#pragma unroll
        for (int rt = 0; rt < 4; ++rt)
#pragma unroll
          for (int ct = 0; ct < 4; ++ct)
            acc[rt][ct] = __builtin_amdgcn_mfma_f32_16x16x32_bf16(
                af[rt], bfr[ct], acc[rt][ct], 0, 0, 0);
      }
      __syncthreads();
    }
#pragma unroll
    for (int rt = 0; rt < 4; ++rt)
#pragma unroll
      for (int r = 0; r < 4; ++r) {
        float v = fmaxf(fmaxf(acc[rt][0][r], acc[rt][1][r]),
                        fmaxf(acc[rt][2][r], acc[rt][3][r]));
        rmax[rt * 4 + r] = fmaxf(rmax[rt * 4 + r], v);
      }
  }

#pragma unroll
  for (int i = 0; i < 16; ++i) {
    float v = rmax[i];
    v = fmaxf(v, __shfl_xor(v, 1));
    v = fmaxf(v, __shfl_xor(v, 2));
    v = fmaxf(v, __shfl_xor(v, 4));
    v = fmaxf(v, __shfl_xor(v, 8));
    rmax[i] = v;
  }
  if (l16 == 0) {
#pragma unroll
    for (int rt = 0; rt < 4; ++rt)
#pragma unroll
      for (int r = 0; r < 4; ++r)
        smax[wc][wr * 64 + rt * 16 + quad * 4 + r] = rmax[rt * 4 + r];
  }
  __syncthreads();
  if (tid < 128) {
    const float v = fmaxf(smax[0][tid], smax[1][tid]);
    pmax[(size_t)(qrow0 + tid) * NCHUNK + blockIdx.y] = v;
  }
}

// ------- Kernel C: reduce partial maxes; uniform rows; flag borderline ------
__global__ void reduce_kernel(const float* __restrict__ pmax,
                              float* __restrict__ out, int* __restrict__ flags) {
  const int idx = blockIdx.x * 256 + threadIdx.x;  // < QN*CN
  const int q = idx >> 7, c = idx & 127;
  const float* p = pmax + (size_t)q * NCHUNK;
  float mx = p[0];
#pragma unroll
  for (int j = 1; j < NCHUNK; ++j) mx = fmaxf(mx, p[j]);
  const bool flag = mx > 0.68f;  // 0.7 minus bf16-error margin (<=~0.01)
  if (c == 0) flags[q] = flag ? 1 : 0;
  if (!flag) out[idx] = 1.0f / 128.0f;
}

// ------- Kernel D: exact fp32 decision for flagged queries (rare path) ------
__global__ void exact_kernel(const float* __restrict__ qe,
                             const float* __restrict__ me,
                             const float* __restrict__ labels,
                             const int* __restrict__ flags,
                             float* __restrict__ out) {
  const int q = blockIdx.x;
  if (!flags[q]) return;
  const int t = threadIdx.x;  // 256
  __shared__ float sred[256];
  __shared__ int sidx[256];
  __shared__ float wsum[4];
  const float* qr = qe + (size_t)q * DN;
  float ss = 0.f;
  for (int i = t; i < DN; i += 256) ss += qr[i] * qr[i];
#pragma unroll
  for (int m = 1; m < 64; m <<= 1) ss += __shfl_xor(ss, m);
  if ((t & 63) == 0) wsum[t >> 6] = ss;
  __syncthreads();
  const float qnorm = fmaxf(sqrtf(wsum[0] + wsum[1] + wsum[2] + wsum[3]), 1e-8f);

  float best = -3.0e38f;
  int bidx = 0x7fffffff;
  for (int j = t; j < MN; j += 256) {
    const float* mr = me + (size_t)j * DN;
    float dot = 0.f, ms = 0.f;
    for (int k = 0; k < DN; ++k) {
      float a = qr[k], b = mr[k];
      dot += a * b;
      ms += b * b;
    }
    const float sim = dot / (qnorm * fmaxf(sqrtf(ms), 1e-8f));
    if (sim > best) { best = sim; bidx = j; }  // strict > keeps first index
  }
  sred[t] = best;
  sidx[t] = bidx;
  __syncthreads();
  for (int s = 128; s > 0; s >>= 1) {
    if (t < s) {
      const float ov = sred[t + s];
      const int oi = sidx[t + s];
      if (ov > sred[t] || (ov == sred[t] && oi < sidx[t])) {
        sred[t] = ov;
        sidx[t] = oi;
      }
    }
    __syncthreads();
  }
  const float mx = sred[0];
  const int mi = sidx[0];
  if (t < 128)
    out[(size_t)q * CN + t] =
        (mx > 0.7f) ? labels[(size_t)mi * CN + t] : (1.0f / 128.0f);
}

extern "C" void kernel_launch(void* const* d_in, const int* in_sizes, int n_in,
                              void* d_out, int out_size, void* d_ws,
                              size_t ws_size, hipStream_t stream) {
  const float* qe = (const float*)d_in[0];  // [4096,384] f32
  const float* me = (const float*)d_in[1];  // [65536,384] f32
  const float* lb = (const float*)d_in[2];  // [65536,128] f32
  float* out = (float*)d_out;               // [4096,128] f32

  char* ws = (char*)d_ws;
  const size_t OFF_QN = 0;
  const size_t OFF_MN = OFF_QN + (size_t)QN * DN * 2;             // 3,145,728
  const size_t OFF_PMAX = OFF_MN + (size_t)MN * DN * 2;           // +50,331,648
  const size_t OFF_FLAGS = OFF_PMAX + (size_t)QN * NCHUNK * 4;    // +524,288
  unsigned short* qn = (unsigned short*)(ws + OFF_QN);
  unsigned short* mn = (unsigned short*)(ws + OFF_MN);
  float* pmax = (float*)(ws + OFF_PMAX);
  int* flags = (int*)(ws + OFF_FLAGS);

  nrm_kernel<<<QN / 4, 256, 0, stream>>>(qe, qn, QN);
  nrm_kernel<<<MN / 4, 256, 0, stream>>>(me, mn, MN);
  gemm_max_kernel<<<dim3(QN / 128, NCHUNK), 256, 0, stream>>>(qn, mn, pmax);
  reduce_kernel<<<(QN * CN) / 256, 256, 0, stream>>>(pmax, out, flags);
  exact_kernel<<<QN, 256, 0, stream>>>(qe, me, lb, flags, out);
}

// Round 3
// 294.879 us; speedup vs baseline: 1.5068x; 1.3605x over previous
//
#include <hip/hip_runtime.h>
#include <math.h>

// Problem constants
#define QN 4096
#define MN 65536
#define DN 384
#define CN 128
#define NCHUNK 32                 // m-chunks (grid.y of GEMM)
#define MROWS_PER_CHUNK (MN / NCHUNK)   // 2048
#define MT_PER (MROWS_PER_CHUNK / 128)  // 16 m-tiles per block

typedef __attribute__((ext_vector_type(8))) int i32x8;
typedef __attribute__((ext_vector_type(4))) int i32x4;
typedef __attribute__((ext_vector_type(4))) float f32x4;

// f32 -> OCP e4m3fn (gfx950 v_cvt_pk_fp8_f32 is OCP on this chip)
__device__ __forceinline__ unsigned char f2fp8(float f) {
  return (unsigned char)(__builtin_amdgcn_cvt_pk_fp8_f32(f, 0.f, 0, false) & 0xff);
}

__device__ __forceinline__ void async16(const void* g, void* l) {
  __builtin_amdgcn_global_load_lds(
      (const __attribute__((address_space(1))) unsigned int*)g,
      (__attribute__((address_space(3))) unsigned int*)l, 16, 0, 0);
}

// ------- Kernel A: L2-normalize rows (q then m) -> fp8, one wave per row ---
__global__ __launch_bounds__(256) void nrm_kernel(const float* __restrict__ qe,
                                                  const float* __restrict__ me,
                                                  unsigned char* __restrict__ yq,
                                                  unsigned char* __restrict__ ym) {
  const int row = blockIdx.x * 4 + (threadIdx.x >> 6);
  const int lane = threadIdx.x & 63;
  const float* xr;
  unsigned char* yr;
  if (row < QN) {
    xr = qe + (size_t)row * DN;
    yr = yq + (size_t)row * DN;
  } else {
    xr = me + (size_t)(row - QN) * DN;
    yr = ym + (size_t)(row - QN) * DN;
  }
  float v[6];
  float ss = 0.f;
#pragma unroll
  for (int i = 0; i < 6; ++i) {
    v[i] = xr[lane + i * 64];
    ss += v[i] * v[i];
  }
#pragma unroll
  for (int m = 1; m < 64; m <<= 1) ss += __shfl_xor(ss, m);
  const float scale = 1.0f / fmaxf(sqrtf(ss), 1e-8f);
#pragma unroll
  for (int i = 0; i < 6; ++i) yr[lane + i * 64] = f2fp8(v[i] * scale);
}

// ------- Kernel B: MX-fp8 (scale=1.0) MFMA GEMM with fused row-max --------
// K=128 per MFMA (mfma_scale_f32_16x16x128_f8f6f4, fmt=fp8, scales=0x7f=1.0).
// LDS rows are 128 B = 8 chunks of 16 B; chunk (r*8+j) holds global chunk
// j^(r&7) (XOR swizzle -> 2-way banks = free; verified 0 conflicts in R2).
__global__ __launch_bounds__(256, 2) void gemm_max_kernel(
    const unsigned char* __restrict__ qn8, const unsigned char* __restrict__ mn8,
    float* __restrict__ pmax) {
  __shared__ unsigned char As[128 * 128];  // 16 KB
  __shared__ unsigned char Bs[128 * 128];  // 16 KB
  __shared__ float smax[2][128];

  const int tid = threadIdx.x;
  const int wave = tid >> 6, lane = tid & 63;
  const int wr = wave >> 1, wc = wave & 1;       // 2x2 wave grid, 64x64 each
  const int quad = lane >> 4, l16 = lane & 15;
  const int r7 = l16 & 7;
  const int qrow0 = blockIdx.x * 128;
  const int mchunk0 = blockIdx.y * MROWS_PER_CHUNK;

  const int srow = lane >> 3;                    // staging: 8 rows / issue
  const int scol = ((lane & 7) ^ srow) * 16;     // swizzled source byte-chunk

  float rmax[16];
#pragma unroll
  for (int i = 0; i < 16; ++i) rmax[i] = -3.0e38f;

#pragma unroll 1
  for (int mt = 0; mt < MT_PER; ++mt) {
    const int mrow0 = mchunk0 + mt * 128;
    f32x4 acc[4][4];
#pragma unroll
    for (int rt = 0; rt < 4; ++rt)
#pragma unroll
      for (int ct = 0; ct < 4; ++ct) acc[rt][ct] = (f32x4){0.f, 0.f, 0.f, 0.f};

#pragma unroll 1
    for (int kc = 0; kc < DN / 128; ++kc) {
      const int k0 = kc * 128;  // byte offset (1 B / element)
#pragma unroll
      for (int i = 0; i < 4; ++i) {
        const int rbase = wave * 32 + i * 8;
        const unsigned char* ga =
            qn8 + (size_t)(qrow0 + rbase + srow) * DN + (k0 + scol);
        async16(ga, &As[rbase * 128]);
        const unsigned char* gb =
            mn8 + (size_t)(mrow0 + rbase + srow) * DN + (k0 + scol);
        async16(gb, &Bs[rbase * 128]);
      }
      __syncthreads();
      i32x8 af[4], bfr[4];
#pragma unroll
      for (int rt = 0; rt < 4; ++rt) {
        const unsigned char* p = &As[(wr * 64 + rt * 16 + l16) * 128];
        i32x4 lo = *(const i32x4*)&p[((quad * 2 + 0) ^ r7) * 16];
        i32x4 hi = *(const i32x4*)&p[((quad * 2 + 1) ^ r7) * 16];
        af[rt][0] = lo[0]; af[rt][1] = lo[1]; af[rt][2] = lo[2]; af[rt][3] = lo[3];
        af[rt][4] = hi[0]; af[rt][5] = hi[1]; af[rt][6] = hi[2]; af[rt][7] = hi[3];
      }
#pragma unroll
      for (int ct = 0; ct < 4; ++ct) {
        const unsigned char* p = &Bs[(wc * 64 + ct * 16 + l16) * 128];
        i32x4 lo = *(const i32x4*)&p[((quad * 2 + 0) ^ r7) * 16];
        i32x4 hi = *(const i32x4*)&p[((quad * 2 + 1) ^ r7) * 16];
        bfr[ct][0] = lo[0]; bfr[ct][1] = lo[1]; bfr[ct][2] = lo[2]; bfr[ct][3] = lo[3];
        bfr[ct][4] = hi[0]; bfr[ct][5] = hi[1]; bfr[ct][6] = hi[2]; bfr[ct][7] = hi[3];
      }
#pragma unroll
      for (int rt = 0; rt < 4; ++rt)
#pragma unroll
        for (int ct = 0; ct < 4; ++ct)
          acc[rt][ct] = __builtin_amdgcn_mfma_scale_f32_16x16x128_f8f6f4(
              af[rt], bfr[ct], acc[rt][ct], 0, 0,  // fmtA=fp8, fmtB=fp8
              0, 0x7f7f7f7f, 0, 0x7f7f7f7f);       // scales = 1.0 (e8m0 127)
      __syncthreads();
    }
#pragma unroll
    for (int rt = 0; rt < 4; ++rt)
#pragma unroll
      for (int r = 0; r < 4; ++r) {
        float v = fmaxf(fmaxf(acc[rt][0][r], acc[rt][1][r]),
                        fmaxf(acc[rt][2][r], acc[rt][3][r]));
        rmax[rt * 4 + r] = fmaxf(rmax[rt * 4 + r], v);
      }
  }

#pragma unroll
  for (int i = 0; i < 16; ++i) {
    float v = rmax[i];
    v = fmaxf(v, __shfl_xor(v, 1));
    v = fmaxf(v, __shfl_xor(v, 2));
    v = fmaxf(v, __shfl_xor(v, 4));
    v = fmaxf(v, __shfl_xor(v, 8));
    rmax[i] = v;
  }
  if (l16 == 0) {
#pragma unroll
    for (int rt = 0; rt < 4; ++rt)
#pragma unroll
      for (int r = 0; r < 4; ++r)
        smax[wc][wr * 64 + rt * 16 + quad * 4 + r] = rmax[rt * 4 + r];
  }
  __syncthreads();
  if (tid < 128) {
    const float v = fmaxf(smax[0][tid], smax[1][tid]);
    pmax[(size_t)(qrow0 + tid) * NCHUNK + blockIdx.y] = v;
  }
}

// ------- Kernel C: reduce partials; uniform row OR exact fp32 re-check -----
// Flag threshold 0.5 = 0.7 minus worst-case fp8 sim error (~0.15) + margin.
__global__ __launch_bounds__(256) void decide_kernel(
    const float* __restrict__ pmax, const float* __restrict__ qe,
    const float* __restrict__ me, const float* __restrict__ labels,
    float* __restrict__ out) {
  const int q = blockIdx.x;
  const int t = threadIdx.x;  // 256
  __shared__ float smx;
  if (t < 64) {
    float v = (t < NCHUNK) ? pmax[(size_t)q * NCHUNK + t] : -3.0e38f;
#pragma unroll
    for (int m = 1; m < 64; m <<= 1) v = fmaxf(v, __shfl_xor(v, m));
    if (t == 0) smx = v;
  }
  __syncthreads();
  if (smx <= 0.5f) {  // uniform fast path (expected for all queries)
    if (t < CN) out[(size_t)q * CN + t] = 1.0f / 128.0f;
    return;
  }
  // exact fp32 path (rare / borderline queries only)
  __shared__ float sred[256];
  __shared__ int sidx[256];
  __shared__ float wsum[4];
  const float* qr = qe + (size_t)q * DN;
  float ss = 0.f;
  for (int i = t; i < DN; i += 256) ss += qr[i] * qr[i];
#pragma unroll
  for (int m = 1; m < 64; m <<= 1) ss += __shfl_xor(ss, m);
  if ((t & 63) == 0) wsum[t >> 6] = ss;
  __syncthreads();
  const float qnorm = fmaxf(sqrtf(wsum[0] + wsum[1] + wsum[2] + wsum[3]), 1e-8f);

  float best = -3.0e38f;
  int bidx = 0x7fffffff;
  for (int j = t; j < MN; j += 256) {
    const float* mr = me + (size_t)j * DN;
    float dot = 0.f, ms = 0.f;
    for (int k = 0; k < DN; ++k) {
      float a = qr[k], b = mr[k];
      dot += a * b;
      ms += b * b;
    }
    const float sim = dot / (qnorm * fmaxf(sqrtf(ms), 1e-8f));
    if (sim > best) { best = sim; bidx = j; }  // strict > keeps first index
  }
  sred[t] = best;
  sidx[t] = bidx;
  __syncthreads();
  for (int s = 128; s > 0; s >>= 1) {
    if (t < s) {
      const float ov = sred[t + s];
      const int oi = sidx[t + s];
      if (ov > sred[t] || (ov == sred[t] && oi < sidx[t])) {
        sred[t] = ov;
        sidx[t] = oi;
      }
    }
    __syncthreads();
  }
  const float mx = sred[0];
  const int mi = sidx[0];
  if (t < CN)
    out[(size_t)q * CN + t] =
        (mx > 0.7f) ? labels[(size_t)mi * CN + t] : (1.0f / 128.0f);
}

extern "C" void kernel_launch(void* const* d_in, const int* in_sizes, int n_in,
                              void* d_out, int out_size, void* d_ws,
                              size_t ws_size, hipStream_t stream) {
  const float* qe = (const float*)d_in[0];  // [4096,384] f32
  const float* me = (const float*)d_in[1];  // [65536,384] f32
  const float* lb = (const float*)d_in[2];  // [65536,128] f32
  float* out = (float*)d_out;               // [4096,128] f32

  char* ws = (char*)d_ws;
  const size_t OFF_QN = 0;
  const size_t OFF_MN = OFF_QN + (size_t)QN * DN;        // 1,572,864
  const size_t OFF_PMAX = OFF_MN + (size_t)MN * DN;      // +25,165,824
  unsigned char* qn8 = (unsigned char*)(ws + OFF_QN);
  unsigned char* mn8 = (unsigned char*)(ws + OFF_MN);
  float* pmax = (float*)(ws + OFF_PMAX);

  nrm_kernel<<<(QN + MN) / 4, 256, 0, stream>>>(qe, me, qn8, mn8);
  gemm_max_kernel<<<dim3(QN / 128, NCHUNK), 256, 0, stream>>>(qn8, mn8, pmax);
  decide_kernel<<<QN, 256, 0, stream>>>(pmax, qe, me, lb, out);
}

// Round 4
// 256.675 us; speedup vs baseline: 1.7311x; 1.1488x over previous
//
#include <hip/hip_runtime.h>
#include <math.h>

// Problem constants
#define QN 4096
#define MN 65536
#define DN 384
#define CN 128
#define NCHUNK 32                 // m-chunks (grid.y of GEMM)
#define MROWS_PER_CHUNK (MN / NCHUNK)   // 2048
#define MT_PER (MROWS_PER_CHUNK / 128)  // 16 m-tiles per block

typedef __attribute__((ext_vector_type(8))) int i32x8;
typedef __attribute__((ext_vector_type(4))) int i32x4;
typedef __attribute__((ext_vector_type(4))) float f32x4;

// f32 -> OCP e4m3fn
__device__ __forceinline__ unsigned char f2fp8(float f) {
  return (unsigned char)(__builtin_amdgcn_cvt_pk_fp8_f32(f, 0.f, 0, false) & 0xff);
}

__device__ __forceinline__ void async16(const void* g, void* l) {
  __builtin_amdgcn_global_load_lds(
      (const __attribute__((address_space(1))) unsigned int*)g,
      (__attribute__((address_space(3))) unsigned int*)l, 16, 0, 0);
}

// ------- Kernel A: L2-normalize rows (q then m) -> fp8, one wave per row ---
__global__ __launch_bounds__(256) void nrm_kernel(const float* __restrict__ qe,
                                                  const float* __restrict__ me,
                                                  unsigned char* __restrict__ yq,
                                                  unsigned char* __restrict__ ym) {
  const int row = blockIdx.x * 4 + (threadIdx.x >> 6);
  const int lane = threadIdx.x & 63;
  const float* xr;
  unsigned char* yr;
  if (row < QN) {
    xr = qe + (size_t)row * DN;
    yr = yq + (size_t)row * DN;
  } else {
    xr = me + (size_t)(row - QN) * DN;
    yr = ym + (size_t)(row - QN) * DN;
  }
  float v[6];
  float ss = 0.f;
#pragma unroll
  for (int i = 0; i < 6; ++i) {
    v[i] = xr[lane + i * 64];
    ss += v[i] * v[i];
  }
#pragma unroll
  for (int m = 1; m < 64; m <<= 1) ss += __shfl_xor(ss, m);
  const float scale = 1.0f / fmaxf(sqrtf(ss), 1e-8f);
#pragma unroll
  for (int i = 0; i < 6; ++i) yr[lane + i * 64] = f2fp8(v[i] * scale);
}

// ------- Kernel B: MX-fp8 GEMM, A-fragments hoisted to registers -----------
// Full-K tiles: LDS holds one 128x384 fp8 tile (48 KB). A is staged once
// (into the same buffer), its 12 fragments (3 kc x 4 rt, 96 VGPRs) are
// hoisted to registers, then the mt loop stages only B (once per mt) and
// runs all 3 kc (48 MFMA) per barrier-pair: 34 barriers/block vs 96.
// XOR swizzle on 16B chunks within each row's 8-chunk group (low 3 bits of
// chunk ^ row) keeps fragment reads bank-uniform.
__global__ __launch_bounds__(256, 2) void gemm_max_kernel(
    const unsigned char* __restrict__ qn8, const unsigned char* __restrict__ mn8,
    float* __restrict__ pmax) {
  __shared__ unsigned char Bs[128 * DN];  // 48 KB, holds A first, then B tiles
  __shared__ float smax[2][128];

  const int tid = threadIdx.x;
  const int wave = tid >> 6, lane = tid & 63;
  const int wr = wave >> 1, wc = wave & 1;       // 2x2 wave grid, 64x64 each
  const int quad = lane >> 4, l16 = lane & 15;
  const int r7 = l16 & 7;
  const int qrow0 = blockIdx.x * 128;
  const int mchunk0 = blockIdx.y * MROWS_PER_CHUNK;

  // staging source offsets: 12 issues x (row, swizzled chunk) per thread
  int srcoff[12];
#pragma unroll
  for (int i = 0; i < 12; ++i) {
    const int ci = i * 256 + tid;          // flat 16B-chunk index 0..3071
    const int row = ci / 24;               // 24 chunks per 384B row
    const int j = ci - row * 24;
    const int gj = (j & 24) | ((j ^ row) & 7);  // global chunk (XOR swizzle)
    srcoff[i] = row * DN + gj * 16;
  }
  // wave-uniform LDS staging bases
  unsigned char* ldsbase[12];
#pragma unroll
  for (int i = 0; i < 12; ++i) ldsbase[i] = &Bs[(i * 256 + wave * 64) * 16];

  float rmax[16];
#pragma unroll
  for (int i = 0; i < 16; ++i) rmax[i] = -3.0e38f;

  // ---- stage A tile once, hoist all fragments to registers ----
  {
    const unsigned char* abase = qn8 + (size_t)qrow0 * DN;
#pragma unroll
    for (int i = 0; i < 12; ++i) async16(abase + srcoff[i], ldsbase[i]);
  }
  __syncthreads();
  i32x8 afr[3][4];
#pragma unroll
  for (int kc = 0; kc < 3; ++kc)
#pragma unroll
    for (int rt = 0; rt < 4; ++rt) {
      const unsigned char* p = &Bs[(wr * 64 + rt * 16 + l16) * DN];
      const int clo = kc * 8 + ((quad * 2 + 0) ^ r7);
      const int chi = kc * 8 + ((quad * 2 + 1) ^ r7);
      i32x4 lo = *(const i32x4*)&p[clo * 16];
      i32x4 hi = *(const i32x4*)&p[chi * 16];
      afr[kc][rt][0] = lo[0]; afr[kc][rt][1] = lo[1];
      afr[kc][rt][2] = lo[2]; afr[kc][rt][3] = lo[3];
      afr[kc][rt][4] = hi[0]; afr[kc][rt][5] = hi[1];
      afr[kc][rt][6] = hi[2]; afr[kc][rt][7] = hi[3];
    }
  __syncthreads();

  // ---- mt loop: stage B full-K once, compute 48 MFMA ----
#pragma unroll 1
  for (int mt = 0; mt < MT_PER; ++mt) {
    const unsigned char* bbase = mn8 + (size_t)(mchunk0 + mt * 128) * DN;
#pragma unroll
    for (int i = 0; i < 12; ++i) async16(bbase + srcoff[i], ldsbase[i]);

    f32x4 acc[4][4];
#pragma unroll
    for (int rt = 0; rt < 4; ++rt)
#pragma unroll
      for (int ct = 0; ct < 4; ++ct) acc[rt][ct] = (f32x4){0.f, 0.f, 0.f, 0.f};

    __syncthreads();
#pragma unroll
    for (int kc = 0; kc < 3; ++kc) {
      i32x8 bfr[4];
#pragma unroll
      for (int ct = 0; ct < 4; ++ct) {
        const unsigned char* p = &Bs[(wc * 64 + ct * 16 + l16) * DN];
        const int clo = kc * 8 + ((quad * 2 + 0) ^ r7);
        const int chi = kc * 8 + ((quad * 2 + 1) ^ r7);
        i32x4 lo = *(const i32x4*)&p[clo * 16];
        i32x4 hi = *(const i32x4*)&p[chi * 16];
        bfr[ct][0] = lo[0]; bfr[ct][1] = lo[1];
        bfr[ct][2] = lo[2]; bfr[ct][3] = lo[3];
        bfr[ct][4] = hi[0]; bfr[ct][5] = hi[1];
        bfr[ct][6] = hi[2]; bfr[ct][7] = hi[3];
      }
#pragma unroll
      for (int rt = 0; rt < 4; ++rt)
#pragma unroll
        for (int ct = 0; ct < 4; ++ct)
          acc[rt][ct] = __builtin_amdgcn_mfma_scale_f32_16x16x128_f8f6f4(
              afr[kc][rt], bfr[ct], acc[rt][ct], 0, 0,  // fmtA=fp8, fmtB=fp8
              0, 0x7f7f7f7f, 0, 0x7f7f7f7f);            // scales = 1.0
    }
    __syncthreads();

#pragma unroll
    for (int rt = 0; rt < 4; ++rt)
#pragma unroll
      for (int r = 0; r < 4; ++r) {
        float v = fmaxf(fmaxf(acc[rt][0][r], acc[rt][1][r]),
                        fmaxf(acc[rt][2][r], acc[rt][3][r]));
        rmax[rt * 4 + r] = fmaxf(rmax[rt * 4 + r], v);
      }
  }

#pragma unroll
  for (int i = 0; i < 16; ++i) {
    float v = rmax[i];
    v = fmaxf(v, __shfl_xor(v, 1));
    v = fmaxf(v, __shfl_xor(v, 2));
    v = fmaxf(v, __shfl_xor(v, 4));
    v = fmaxf(v, __shfl_xor(v, 8));
    rmax[i] = v;
  }
  if (l16 == 0) {
#pragma unroll
    for (int rt = 0; rt < 4; ++rt)
#pragma unroll
      for (int r = 0; r < 4; ++r)
        smax[wc][wr * 64 + rt * 16 + quad * 4 + r] = rmax[rt * 4 + r];
  }
  __syncthreads();
  if (tid < 128) {
    const float v = fmaxf(smax[0][tid], smax[1][tid]);
    pmax[(size_t)(qrow0 + tid) * NCHUNK + blockIdx.y] = v;
  }
}

// ------- Kernel C: reduce partials; uniform row OR exact fp32 re-check -----
__global__ __launch_bounds__(256) void decide_kernel(
    const float* __restrict__ pmax, const float* __restrict__ qe,
    const float* __restrict__ me, const float* __restrict__ labels,
    float* __restrict__ out) {
  const int q = blockIdx.x;
  const int t = threadIdx.x;  // 256
  __shared__ float smx;
  if (t < 64) {
    float v = (t < NCHUNK) ? pmax[(size_t)q * NCHUNK + t] : -3.0e38f;
#pragma unroll
    for (int m = 1; m < 64; m <<= 1) v = fmaxf(v, __shfl_xor(v, m));
    if (t == 0) smx = v;
  }
  __syncthreads();
  if (smx <= 0.5f) {  // uniform fast path (expected for all queries)
    if (t < CN) out[(size_t)q * CN + t] = 1.0f / 128.0f;
    return;
  }
  // exact fp32 path (rare / borderline queries only)
  __shared__ float sred[256];
  __shared__ int sidx[256];
  __shared__ float wsum[4];
  const float* qr = qe + (size_t)q * DN;
  float ss = 0.f;
  for (int i = t; i < DN; i += 256) ss += qr[i] * qr[i];
#pragma unroll
  for (int m = 1; m < 64; m <<= 1) ss += __shfl_xor(ss, m);
  if ((t & 63) == 0) wsum[t >> 6] = ss;
  __syncthreads();
  const float qnorm = fmaxf(sqrtf(wsum[0] + wsum[1] + wsum[2] + wsum[3]), 1e-8f);

  float best = -3.0e38f;
  int bidx = 0x7fffffff;
  for (int j = t; j < MN; j += 256) {
    const float* mr = me + (size_t)j * DN;
    float dot = 0.f, ms = 0.f;
    for (int k = 0; k < DN; ++k) {
      float a = qr[k], b = mr[k];
      dot += a * b;
      ms += b * b;
    }
    const float sim = dot / (qnorm * fmaxf(sqrtf(ms), 1e-8f));
    if (sim > best) { best = sim; bidx = j; }  // strict > keeps first index
  }
  sred[t] = best;
  sidx[t] = bidx;
  __syncthreads();
  for (int s = 128; s > 0; s >>= 1) {
    if (t < s) {
      const float ov = sred[t + s];
      const int oi = sidx[t + s];
      if (ov > sred[t] || (ov == sred[t] && oi < sidx[t])) {
        sred[t] = ov;
        sidx[t] = oi;
      }
    }
    __syncthreads();
  }
  const float mx = sred[0];
  const int mi = sidx[0];
  if (t < CN)
    out[(size_t)q * CN + t] =
        (mx > 0.7f) ? labels[(size_t)mi * CN + t] : (1.0f / 128.0f);
}

extern "C" void kernel_launch(void* const* d_in, const int* in_sizes, int n_in,
                              void* d_out, int out_size, void* d_ws,
                              size_t ws_size, hipStream_t stream) {
  const float* qe = (const float*)d_in[0];  // [4096,384] f32
  const float* me = (const float*)d_in[1];  // [65536,384] f32
  const float* lb = (const float*)d_in[2];  // [65536,128] f32
  float* out = (float*)d_out;               // [4096,128] f32

  char* ws = (char*)d_ws;
  const size_t OFF_QN = 0;
  const size_t OFF_MN = OFF_QN + (size_t)QN * DN;        // 1,572,864
  const size_t OFF_PMAX = OFF_MN + (size_t)MN * DN;      // +25,165,824
  unsigned char* qn8 = (unsigned char*)(ws + OFF_QN);
  unsigned char* mn8 = (unsigned char*)(ws + OFF_MN);
  float* pmax = (float*)(ws + OFF_PMAX);

  nrm_kernel<<<(QN + MN) / 4, 256, 0, stream>>>(qe, me, qn8, mn8);
  gemm_max_kernel<<<dim3(QN / 128, NCHUNK), 256, 0, stream>>>(qn8, mn8, pmax);
  decide_kernel<<<QN, 256, 0, stream>>>(pmax, qe, me, lb, out);
}